// Round 2
// baseline (1392.339 us; speedup 1.0000x reference)
//
#include <hip/hip_runtime.h>
#include <hip/hip_bf16.h>
#include <type_traits>

#define B_    256
#define N_    196
#define DIM_  384
#define H_    12
#define KD_   32
#define VD_   32
#define F_    1152          // H * (2*KD + VD)
#define ROWS_ (B_ * N_)     // 50176
#define SCALE_ 0.17677669529663687f
#define EPS_  1e-5f

typedef __hip_bfloat16 bf16;

__device__ __forceinline__ float u2f(unsigned short u) {
    return __uint_as_float(((unsigned)u) << 16);          // bf16 bits -> f32
}
__device__ __forceinline__ float b2f(bf16 v) { return __bfloat162float(v); }
__device__ __forceinline__ bf16  f2b(float v) { return __float2bfloat16(v); }

// ---------------------------------------------------------------------------
// Kernel 1: LayerNorm. fp32 in, bf16 out. One block per row, 384 threads.
// ---------------------------------------------------------------------------
__global__ __launch_bounds__(384) void ln_kernel(const float* __restrict__ x,
                                                 const float* __restrict__ w,
                                                 const float* __restrict__ bvec,
                                                 bf16* __restrict__ xn) {
    const int row = blockIdx.x;
    const int t   = threadIdx.x;
    const float v = x[(size_t)row * DIM_ + t];
    float s = v, s2 = v * v;
    #pragma unroll
    for (int o = 32; o > 0; o >>= 1) {
        s  += __shfl_xor(s, o);
        s2 += __shfl_xor(s2, o);
    }
    __shared__ float ws_[6], ws2_[6];
    __shared__ float mu_s, rs_s;
    const int wv = t >> 6;
    if ((t & 63) == 0) { ws_[wv] = s; ws2_[wv] = s2; }
    __syncthreads();
    if (t == 0) {
        float S = 0.f, S2 = 0.f;
        #pragma unroll
        for (int i = 0; i < 6; i++) { S += ws_[i]; S2 += ws2_[i]; }
        const float mu  = S / DIM_;
        const float var = S2 / DIM_ - mu * mu;
        mu_s = mu;
        rs_s = rsqrtf(var + EPS_);
    }
    __syncthreads();
    xn[(size_t)row * DIM_ + t] = f2b((v - mu_s) * rs_s * w[t] + bvec[t]);
}

// ---------------------------------------------------------------------------
// Kernel 2/4: C[M,Nout] = A[M,K] @ Wt[Nout,K]^T + bias.
// A bf16 (workspace), Wt/bias fp32 (input weights), OutT = bf16 or float.
// 64x64 tile, BK=16, 256 threads, 4x4 acc. k-major padded LDS:
// inner loop = 2x ds_read_b128 + 16 FMA per k-step.
// ---------------------------------------------------------------------------
template <typename OutT>
__global__ __launch_bounds__(256) void gemm_bt(const bf16* __restrict__ A,
                                               const float* __restrict__ Wt,
                                               const float* __restrict__ bias,
                                               OutT* __restrict__ C,
                                               int M, int Nout, int K) {
    __shared__ __align__(16) float As[16][68];   // [k][m], pad 68 for banks+align
    __shared__ __align__(16) float Bs[16][68];   // [k][n]
    const int tid = threadIdx.x;
    const int tx  = tid & 15;
    const int ty  = tid >> 4;
    const int bm  = blockIdx.x * 64;
    const int bn  = blockIdx.y * 64;
    const int r   = tid >> 2;          // 0..63   staging row within tile
    const int ci  = (tid & 3) * 4;     // 0,4,8,12 staging k-offset

    float acc[4][4] = {};

    for (int k0 = 0; k0 < K; k0 += 16) {
        {
            const ushort4 ua = *(const ushort4*)(A + (size_t)(bm + r) * K + k0 + ci);
            As[ci + 0][r] = u2f(ua.x);
            As[ci + 1][r] = u2f(ua.y);
            As[ci + 2][r] = u2f(ua.z);
            As[ci + 3][r] = u2f(ua.w);
            const float4 wb = *(const float4*)(Wt + (size_t)(bn + r) * K + k0 + ci);
            Bs[ci + 0][r] = wb.x;
            Bs[ci + 1][r] = wb.y;
            Bs[ci + 2][r] = wb.z;
            Bs[ci + 3][r] = wb.w;
        }
        __syncthreads();
        #pragma unroll
        for (int kk = 0; kk < 16; kk++) {
            const float4 a4 = *(const float4*)&As[kk][ty * 4];
            const float4 b4 = *(const float4*)&Bs[kk][tx * 4];
            const float a[4] = {a4.x, a4.y, a4.z, a4.w};
            const float b[4] = {b4.x, b4.y, b4.z, b4.w};
            #pragma unroll
            for (int i = 0; i < 4; i++)
                #pragma unroll
                for (int j = 0; j < 4; j++)
                    acc[i][j] += a[i] * b[j];
        }
        __syncthreads();
    }

    #pragma unroll
    for (int i = 0; i < 4; i++) {
        const int rowi = bm + ty * 4 + i;
        #pragma unroll
        for (int j = 0; j < 4; j++) {
            const int col = bn + tx * 4 + j;
            const float v = acc[i][j] + bias[col];
            if constexpr (std::is_same<OutT, bf16>::value)
                C[(size_t)rowi * Nout + col] = f2b(v);
            else
                C[(size_t)rowi * Nout + col] = v;
        }
    }
}

// ---------------------------------------------------------------------------
// Kernel 3: fused attention per (b,h). K,V staged in LDS (fp32); one thread
// per query row; online softmax; bias via idx gather through LDS.
// ---------------------------------------------------------------------------
__global__ __launch_bounds__(256) void attn_kernel(const bf16* __restrict__ qkv,
                                                   const float* __restrict__ biases,
                                                   const int* __restrict__ idxs,
                                                   bf16* __restrict__ out) {
    const int bh = blockIdx.x;
    const int b  = bh / H_;
    const int h  = bh % H_;

    __shared__ __align__(16) float Ks[N_][KD_];
    __shared__ __align__(16) float Vs[N_][VD_];
    __shared__ float bvals[N_];

    const int t = threadIdx.x;

    // stage K and V: 4 bf16 per iteration (ushort4 = 8B loads)
    for (int e = t; e < N_ * 16; e += 256) {
        const int n = e >> 4;
        const int c = (e & 15) * 4;    // 0..60 over the 64 bf16 of K|V
        const size_t base = ((size_t)(b * N_ + n) * H_ + h) * 96;
        const ushort4 u = *(const ushort4*)(qkv + base + 32 + c);
        float* dst = (c < 32) ? &Ks[n][c] : &Vs[n][c - 32];
        dst[0] = u2f(u.x); dst[1] = u2f(u.y); dst[2] = u2f(u.z); dst[3] = u2f(u.w);
    }
    if (t < N_) bvals[t] = biases[h * N_ + t];
    __syncthreads();

    if (t < N_) {
        const int n = t;
        const size_t base = ((size_t)(b * N_ + n) * H_ + h) * 96;
        float q[KD_];
        #pragma unroll
        for (int c = 0; c < KD_; c += 4) {
            const ushort4 u = *(const ushort4*)(qkv + base + c);
            q[c + 0] = u2f(u.x) * SCALE_;
            q[c + 1] = u2f(u.y) * SCALE_;
            q[c + 2] = u2f(u.z) * SCALE_;
            q[c + 3] = u2f(u.w) * SCALE_;
        }

        float m_run = -1e30f;
        float l_run = 0.f;
        float acc[VD_];
        #pragma unroll
        for (int v = 0; v < VD_; v++) acc[v] = 0.f;

        const int* idxrow = idxs + n * N_;
        for (int m = 0; m < N_; m++) {
            float s = 0.f;
            #pragma unroll
            for (int c = 0; c < KD_; c++) s += q[c] * Ks[m][c];
            s += bvals[idxrow[m]];
            const float mnew = fmaxf(m_run, s);
            const float corr = __expf(m_run - mnew);
            const float p    = __expf(s - mnew);
            l_run = l_run * corr + p;
            #pragma unroll
            for (int v = 0; v < VD_; v++) acc[v] = acc[v] * corr + p * Vs[m][v];
            m_run = mnew;
        }
        const float inv = 1.f / l_run;
        const size_t ob = (size_t)(b * N_ + n) * DIM_ + h * 32;
        #pragma unroll
        for (int v = 0; v < VD_; v++) out[ob + v] = f2b(acc[v] * inv);
    }
}

// ---------------------------------------------------------------------------
extern "C" void kernel_launch(void* const* d_in, const int* in_sizes, int n_in,
                              void* d_out, int out_size, void* d_ws, size_t ws_size,
                              hipStream_t stream) {
    const float* x        = (const float*)d_in[0];
    const float* norm_w   = (const float*)d_in[1];
    const float* norm_b   = (const float*)d_in[2];
    const float* qkv_w    = (const float*)d_in[3];
    const float* qkv_b    = (const float*)d_in[4];
    const float* att_bias = (const float*)d_in[5];
    const float* proj_w   = (const float*)d_in[6];
    const float* proj_b   = (const float*)d_in[7];
    const int*   bias_idx = (const int*)d_in[8];
    float* out = (float*)d_out;

    char* ws = (char*)d_ws;
    bf16* xn       = (bf16*)ws;                                        // 50176*384  bf16
    bf16* qkv      = (bf16*)(ws + (size_t)ROWS_ * DIM_ * 2);           // 50176*1152 bf16
    bf16* attn_out = (bf16*)(ws + (size_t)ROWS_ * DIM_ * 2
                                + (size_t)ROWS_ * F_ * 2);             // 50176*384  bf16

    ln_kernel<<<ROWS_, 384, 0, stream>>>(x, norm_w, norm_b, xn);
    gemm_bt<bf16><<<dim3(ROWS_ / 64, F_ / 64), 256, 0, stream>>>(
        xn, qkv_w, qkv_b, qkv, ROWS_, F_, DIM_);
    attn_kernel<<<B_ * H_, 256, 0, stream>>>(qkv, att_bias, bias_idx, attn_out);
    gemm_bt<float><<<dim3(ROWS_ / 64, DIM_ / 64), 256, 0, stream>>>(
        attn_out, proj_w, proj_b, out, ROWS_, DIM_, DIM_);
}

// Round 3
// 477.194 us; speedup vs baseline: 2.9178x; 2.9178x over previous
//
#include <hip/hip_runtime.h>

#define B_    256
#define N_    196
#define NP_   208      // 13*16 padded sequence
#define NP2_  224      // 7*32 padded PV reduction dim
#define PSTR_ 232      // P/Vt LDS row stride (+8 pad -> 2-way banks)
#define KSTR_ 40       // K LDS row stride (+8 pad)
#define DIM_  384
#define H_    12
#define KD_   32
#define VD_   32
#define F_    1152
#define ROWS_ (B_ * N_)
#define SCALE_ 0.17677669529663687f
#define EPS_  1e-5f

typedef __bf16 bf16_t;
typedef __bf16 bf16x4 __attribute__((ext_vector_type(4)));
typedef __bf16 bf16x8 __attribute__((ext_vector_type(8)));
typedef float  f32x4  __attribute__((ext_vector_type(4)));

__device__ __forceinline__ f32x4 mfma16(bf16x8 a, bf16x8 b, f32x4 c) {
    return __builtin_amdgcn_mfma_f32_16x16x32_bf16(a, b, c, 0, 0, 0);
}

// ---------------------------------------------------------------------------
// LayerNorm: fp32 in -> bf16 out. One block per row, 384 threads.
// ---------------------------------------------------------------------------
__global__ __launch_bounds__(384) void ln_kernel(const float* __restrict__ x,
                                                 const float* __restrict__ w,
                                                 const float* __restrict__ bvec,
                                                 bf16_t* __restrict__ xn) {
    const int row = blockIdx.x;
    const int t   = threadIdx.x;
    const float v = x[(size_t)row * DIM_ + t];
    float s = v, s2 = v * v;
    #pragma unroll
    for (int o = 32; o > 0; o >>= 1) {
        s  += __shfl_xor(s, o);
        s2 += __shfl_xor(s2, o);
    }
    __shared__ float ws_[6], ws2_[6];
    __shared__ float mu_s, rs_s;
    if ((t & 63) == 0) { ws_[t >> 6] = s; ws2_[t >> 6] = s2; }
    __syncthreads();
    if (t == 0) {
        float S = 0.f, S2 = 0.f;
        #pragma unroll
        for (int i = 0; i < 6; i++) { S += ws_[i]; S2 += ws2_[i]; }
        const float mu  = S / DIM_;
        const float var = S2 / DIM_ - mu * mu;
        mu_s = mu;
        rs_s = rsqrtf(var + EPS_);
    }
    __syncthreads();
    xn[(size_t)row * DIM_ + t] = (bf16_t)((v - mu_s) * rs_s * w[t] + bvec[t]);
}

// ---------------------------------------------------------------------------
// Precompute biasmat[h][n][m] (m padded to 208, pad = -1e30) as bf16.
// ---------------------------------------------------------------------------
__global__ __launch_bounds__(256) void bias_gather(const float* __restrict__ biases,
                                                   const int* __restrict__ idxs,
                                                   bf16_t* __restrict__ biasmat) {
    const int e = blockIdx.x * 256 + threadIdx.x;
    if (e >= H_ * N_ * NP_) return;
    const int h = e / (N_ * NP_);
    const int r = e % (N_ * NP_);
    const int n = r / NP_;
    const int m = r % NP_;
    const float v = (m < N_) ? biases[h * N_ + idxs[n * N_ + m]] : -1e30f;
    biasmat[e] = (bf16_t)v;
}

// ---------------------------------------------------------------------------
// MFMA GEMM: C[M][Nout] = A[M][K](bf16) @ Wt[Nout][K]^T(fp32->bf16) + bias.
// 128x128 tile, BK=32, 256 thr (4 waves, each 64x64 = 4x4 frags of 16x16).
// M%128==0, Nout%128==0, K%32==0 guaranteed by problem shapes.
// ---------------------------------------------------------------------------
template <typename OutT>
__global__ __launch_bounds__(256) void gemm_mfma(const bf16_t* __restrict__ A,
                                                 const float* __restrict__ Wt,
                                                 const float* __restrict__ bias,
                                                 OutT* __restrict__ C,
                                                 int M, int Nout, int K) {
    __shared__ __align__(16) bf16_t As[128][KSTR_];
    __shared__ __align__(16) bf16_t Bs[128][KSTR_];
    const int tid  = threadIdx.x;
    const int lane = tid & 63;
    const int wv   = tid >> 6;
    const int wr   = (wv >> 1) * 64;
    const int wc   = (wv & 1) * 64;
    const int ln   = lane & 15;
    const int ko   = lane >> 4;
    const size_t bm = (size_t)blockIdx.x * 128;
    const size_t bn = (size_t)blockIdx.y * 128;

    f32x4 acc[4][4];
    #pragma unroll
    for (int i = 0; i < 4; i++)
        #pragma unroll
        for (int j = 0; j < 4; j++)
            acc[i][j] = (f32x4){0.f, 0.f, 0.f, 0.f};

    for (int k0 = 0; k0 < K; k0 += 32) {
        // stage A tile (bf16, 128x32): 512 x 16B tasks
        #pragma unroll
        for (int q = 0; q < 2; q++) {
            const int idx = q * 256 + tid;
            const int row = idx >> 2;
            const int c8  = (idx & 3) * 8;
            *(uint4*)&As[row][c8] =
                *(const uint4*)(A + (bm + row) * K + k0 + c8);
        }
        // stage W tile (fp32 -> bf16, 128x32): 1024 x float4 tasks
        #pragma unroll
        for (int q = 0; q < 4; q++) {
            const int idx = q * 256 + tid;
            const int row = idx >> 3;
            const int c4  = (idx & 7) * 4;
            const float4 w4 = *(const float4*)(Wt + (bn + row) * K + k0 + c4);
            bf16x4 b4 = {(bf16_t)w4.x, (bf16_t)w4.y, (bf16_t)w4.z, (bf16_t)w4.w};
            *(bf16x4*)&Bs[row][c4] = b4;
        }
        __syncthreads();
        bf16x8 af[4], bfr[4];
        #pragma unroll
        for (int i = 0; i < 4; i++)
            af[i] = *(const bf16x8*)&As[wr + i * 16 + ln][ko * 8];
        #pragma unroll
        for (int j = 0; j < 4; j++)
            bfr[j] = *(const bf16x8*)&Bs[wc + j * 16 + ln][ko * 8];
        #pragma unroll
        for (int i = 0; i < 4; i++)
            #pragma unroll
            for (int j = 0; j < 4; j++)
                acc[i][j] = mfma16(af[i], bfr[j], acc[i][j]);
        __syncthreads();
    }

    #pragma unroll
    for (int j = 0; j < 4; j++) {
        const size_t col = bn + wc + j * 16 + ln;
        const float bcol = bias[col];
        #pragma unroll
        for (int i = 0; i < 4; i++) {
            #pragma unroll
            for (int r = 0; r < 4; r++) {
                const size_t row = bm + wr + i * 16 + ko * 4 + r;
                C[row * Nout + col] = (OutT)(acc[i][j][r] + bcol);
            }
        }
    }
}

// ---------------------------------------------------------------------------
// MFMA attention: one block (4 waves) per (b,h). K in LDS, V transposed in
// LDS; each wave owns 16-row query tiles (t = wv, wv+4, ...), full-row
// softmax in registers (16-lane shfl reduce), P -> LDS (A-layout), PV MFMA.
// ---------------------------------------------------------------------------
__global__ __launch_bounds__(256) void attn_mfma(const bf16_t* __restrict__ qkv,
                                                 const bf16_t* __restrict__ biasmat,
                                                 bf16_t* __restrict__ out) {
    const int b = blockIdx.x / H_;
    const int h = blockIdx.x % H_;
    __shared__ __align__(16) bf16_t Ks[NP_][KSTR_];       // 16640 B
    __shared__ __align__(16) bf16_t Vt[VD_][PSTR_];       // 14848 B
    __shared__ __align__(16) bf16_t Pb[4][16][PSTR_];     // 29696 B
    const int tid  = threadIdx.x;
    const int lane = tid & 63;
    const int wv   = tid >> 6;
    const int ln   = lane & 15;
    const int ko   = lane >> 4;

    // stage K rows (zero-fill padded rows)
    for (int e = tid; e < NP_ * 4; e += 256) {
        const int row = e >> 2;
        const int c8  = (e & 3) * 8;
        uint4 val = make_uint4(0u, 0u, 0u, 0u);
        if (row < N_)
            val = *(const uint4*)(qkv + ((size_t)(b * N_ + row) * H_ + h) * 96 + KD_ + c8);
        *(uint4*)&Ks[row][c8] = val;
    }
    // stage V transposed: thread m handles one source row
    if (tid < NP2_) {
        const int m = tid;
        const bf16_t* src = qkv + ((size_t)(b * N_ + m) * H_ + h) * 96 + 2 * KD_;
        #pragma unroll
        for (int c = 0; c < 4; c++) {
            bf16x8 v8 = {bf16_t(0), bf16_t(0), bf16_t(0), bf16_t(0),
                         bf16_t(0), bf16_t(0), bf16_t(0), bf16_t(0)};
            if (m < N_) v8 = *(const bf16x8*)(src + c * 8);
            #pragma unroll
            for (int j = 0; j < 8; j++) Vt[c * 8 + j][m] = v8[j];
        }
    }
    // zero P buffer (covers the 208..223 PV pad region)
    for (int e = tid; e < (4 * 16 * PSTR_) / 8; e += 256)
        ((uint4*)Pb)[e] = make_uint4(0u, 0u, 0u, 0u);
    __syncthreads();

    for (int t = wv; t < 13; t += 4) {
        // Q fragment (A-layout) straight from global; clamp padded rows
        const int qrow = min(t * 16 + ln, N_ - 1);
        const bf16x8 qf =
            *(const bf16x8*)(qkv + ((size_t)(b * N_ + qrow) * H_ + h) * 96 + ko * 8);

        // scores: 13 tiles of 16x16
        f32x4 sc[13];
        #pragma unroll
        for (int c = 0; c < 13; c++) {
            const bf16x8 kf = *(const bf16x8*)&Ks[c * 16 + ln][ko * 8];
            f32x4 z = {0.f, 0.f, 0.f, 0.f};
            sc[c] = mfma16(qf, kf, z);
        }

        // scale + bias + row max
        float mx[4] = {-1e30f, -1e30f, -1e30f, -1e30f};
        #pragma unroll
        for (int r = 0; r < 4; r++) {
            const int rowc = min(t * 16 + ko * 4 + r, N_ - 1);
            const bf16_t* brow = biasmat + (size_t)(h * N_ + rowc) * NP_;
            #pragma unroll
            for (int c = 0; c < 13; c++) {
                const float s = sc[c][r] * SCALE_ + (float)brow[c * 16 + ln];
                sc[c][r] = s;
                mx[r] = fmaxf(mx[r], s);
            }
        }
        #pragma unroll
        for (int r = 0; r < 4; r++) {
            float m = mx[r];
            m = fmaxf(m, __shfl_xor(m, 1));
            m = fmaxf(m, __shfl_xor(m, 2));
            m = fmaxf(m, __shfl_xor(m, 4));
            m = fmaxf(m, __shfl_xor(m, 8));
            mx[r] = m;
        }
        float sum[4] = {0.f, 0.f, 0.f, 0.f};
        #pragma unroll
        for (int c = 0; c < 13; c++)
            #pragma unroll
            for (int r = 0; r < 4; r++) {
                const float p = __expf(sc[c][r] - mx[r]);
                sc[c][r] = p;
                sum[r] += p;
            }
        #pragma unroll
        for (int r = 0; r < 4; r++) {
            float s = sum[r];
            s += __shfl_xor(s, 1);
            s += __shfl_xor(s, 2);
            s += __shfl_xor(s, 4);
            s += __shfl_xor(s, 8);
            sum[r] = 1.f / s;
        }
        // write normalized P (bf16) into this wave's LDS tile
        #pragma unroll
        for (int c = 0; c < 13; c++)
            #pragma unroll
            for (int r = 0; r < 4; r++)
                Pb[wv][ko * 4 + r][c * 16 + ln] = (bf16_t)(sc[c][r] * sum[r]);
        __builtin_amdgcn_s_waitcnt(0);

        // PV: two 16-col output tiles, K-dim = 224 (7 MFMAs)
        #pragma unroll
        for (int j = 0; j < 2; j++) {
            f32x4 o = {0.f, 0.f, 0.f, 0.f};
            #pragma unroll
            for (int kb = 0; kb < 7; kb++) {
                const bf16x8 pf = *(const bf16x8*)&Pb[wv][ln][kb * 32 + ko * 8];
                const bf16x8 vf = *(const bf16x8*)&Vt[j * 16 + ln][kb * 32 + ko * 8];
                o = mfma16(pf, vf, o);
            }
            #pragma unroll
            for (int r = 0; r < 4; r++) {
                const int row = t * 16 + ko * 4 + r;
                if (row < N_)
                    out[(size_t)(b * N_ + row) * DIM_ + h * VD_ + j * 16 + ln] =
                        (bf16_t)o[r];
            }
        }
    }
}

// ---------------------------------------------------------------------------
extern "C" void kernel_launch(void* const* d_in, const int* in_sizes, int n_in,
                              void* d_out, int out_size, void* d_ws, size_t ws_size,
                              hipStream_t stream) {
    const float* x        = (const float*)d_in[0];
    const float* norm_w   = (const float*)d_in[1];
    const float* norm_b   = (const float*)d_in[2];
    const float* qkv_w    = (const float*)d_in[3];
    const float* qkv_b    = (const float*)d_in[4];
    const float* att_bias = (const float*)d_in[5];
    const float* proj_w   = (const float*)d_in[6];
    const float* proj_b   = (const float*)d_in[7];
    const int*   bias_idx = (const int*)d_in[8];
    float* out = (float*)d_out;

    char* ws = (char*)d_ws;
    bf16_t* xn       = (bf16_t*)ws;
    bf16_t* qkvbuf   = (bf16_t*)(ws + (size_t)ROWS_ * DIM_ * 2);
    bf16_t* attn_out = (bf16_t*)(ws + (size_t)ROWS_ * DIM_ * 2 + (size_t)ROWS_ * F_ * 2);
    bf16_t* biasmat  = (bf16_t*)(ws + (size_t)ROWS_ * DIM_ * 4 + (size_t)ROWS_ * F_ * 2);

    ln_kernel<<<ROWS_, 384, 0, stream>>>(x, norm_w, norm_b, xn);
    bias_gather<<<(H_ * N_ * NP_ + 255) / 256, 256, 0, stream>>>(att_bias, bias_idx, biasmat);
    gemm_mfma<bf16_t><<<dim3(ROWS_ / 128, F_ / 128), 256, 0, stream>>>(
        xn, qkv_w, qkv_b, qkvbuf, ROWS_, F_, DIM_);
    attn_mfma<<<B_ * H_, 256, 0, stream>>>(qkvbuf, biasmat, attn_out);
    gemm_mfma<float><<<dim3(ROWS_ / 128, DIM_ / 128), 256, 0, stream>>>(
        attn_out, proj_w, proj_b, out, ROWS_, DIM_, DIM_);
}

// Round 4
// 372.183 us; speedup vs baseline: 3.7410x; 1.2821x over previous
//
#include <hip/hip_runtime.h>

#define B_    256
#define N_    196
#define NP_   208      // 13*16 padded key count
#define VSTR_ 264      // Vt/Pb row stride in bf16 (264*2B = 132 dwords == 4 mod 32: bank-uniform)
#define DIM_  384
#define H_    12
#define KD_   32
#define VD_   32
#define F_    1152
#define ROWS_ (B_ * N_)
#define SCALE_ 0.17677669529663687f
#define EPS_  1e-5f

typedef __bf16 bf16_t;
typedef __bf16 bf16x2 __attribute__((ext_vector_type(2)));
typedef __bf16 bf16x4 __attribute__((ext_vector_type(4)));
typedef __bf16 bf16x8 __attribute__((ext_vector_type(8)));
typedef float  f32x4  __attribute__((ext_vector_type(4)));

__device__ __forceinline__ f32x4 mfma16(bf16x8 a, bf16x8 b, f32x4 c) {
    return __builtin_amdgcn_mfma_f32_16x16x32_bf16(a, b, c, 0, 0, 0);
}

// async global->LDS, 16B per lane. LDS dest must be wave-uniform base + lane*16.
__device__ __forceinline__ void gl2lds(const bf16_t* g, bf16_t* l) {
    __builtin_amdgcn_global_load_lds(
        (const __attribute__((address_space(1))) void*)g,
        (__attribute__((address_space(3))) void*)l, 16, 0, 0);
}

// ---------------------------------------------------------------------------
// Weight fp32 -> bf16 convert (grid covers exactly n/4 threads' worth).
// ---------------------------------------------------------------------------
__global__ __launch_bounds__(256) void cvt_w(const float* __restrict__ src,
                                             bf16_t* __restrict__ dst) {
    const int i = (blockIdx.x * 256 + threadIdx.x) * 4;
    const float4 v = *(const float4*)(src + i);
    bf16x4 o = {(bf16_t)v.x, (bf16_t)v.y, (bf16_t)v.z, (bf16_t)v.w};
    *(bf16x4*)(dst + i) = o;
}

// ---------------------------------------------------------------------------
// LayerNorm: one wave per row, 4 rows per block. fp32 in -> bf16 out.
// ---------------------------------------------------------------------------
__global__ __launch_bounds__(256) void ln_kernel(const float* __restrict__ x,
                                                 const float* __restrict__ w,
                                                 const float* __restrict__ bvec,
                                                 bf16_t* __restrict__ xn) {
    const int lane = threadIdx.x & 63;
    const int row  = blockIdx.x * 4 + (threadIdx.x >> 6);
    const float* xr = x + (size_t)row * DIM_;
    const float4 a = *(const float4*)(xr + lane * 4);
    const float2 c = *(const float2*)(xr + 256 + lane * 2);
    float s  = a.x + a.y + a.z + a.w + c.x + c.y;
    float s2 = a.x*a.x + a.y*a.y + a.z*a.z + a.w*a.w + c.x*c.x + c.y*c.y;
    #pragma unroll
    for (int o = 32; o > 0; o >>= 1) {
        s  += __shfl_xor(s, o);
        s2 += __shfl_xor(s2, o);
    }
    const float mu = s * (1.f / 384.f);
    const float rs = rsqrtf(s2 * (1.f / 384.f) - mu * mu + EPS_);
    const float4 w4 = *(const float4*)(w + lane * 4);
    const float2 w2 = *(const float2*)(w + 256 + lane * 2);
    const float4 b4 = *(const float4*)(bvec + lane * 4);
    const float2 b2 = *(const float2*)(bvec + 256 + lane * 2);
    bf16_t* orow = xn + (size_t)row * DIM_;
    bf16x4 o4 = {(bf16_t)((a.x - mu) * rs * w4.x + b4.x),
                 (bf16_t)((a.y - mu) * rs * w4.y + b4.y),
                 (bf16_t)((a.z - mu) * rs * w4.z + b4.z),
                 (bf16_t)((a.w - mu) * rs * w4.w + b4.w)};
    *(bf16x4*)(orow + lane * 4) = o4;
    bf16x2 o2 = {(bf16_t)((c.x - mu) * rs * w2.x + b2.x),
                 (bf16_t)((c.y - mu) * rs * w2.y + b2.y)};
    *(bf16x2*)(orow + 256 + lane * 2) = o2;
}

// ---------------------------------------------------------------------------
// biasmat[h][n][m], m padded to 208 with -1e30, bf16.
// ---------------------------------------------------------------------------
__global__ __launch_bounds__(256) void bias_gather(const float* __restrict__ biases,
                                                   const int* __restrict__ idxs,
                                                   bf16_t* __restrict__ biasmat) {
    const int e = blockIdx.x * 256 + threadIdx.x;
    if (e >= H_ * N_ * NP_) return;
    const int h = e / (N_ * NP_);
    const int r = e % (N_ * NP_);
    const int n = r / NP_;
    const int m = r % NP_;
    const float v = (m < N_) ? biases[h * N_ + idxs[n * N_ + m]] : -1e30f;
    biasmat[e] = (bf16_t)v;
}

// ---------------------------------------------------------------------------
// MFMA GEMM (m97 recipe): C[M][Nout] = A[M][K] @ Wt[Nout][K]^T + bias.
// All-bf16 inputs, unpadded [128][32] LDS tiles, global_load_lds staging.
// 256 threads = 4 waves, each computing 64x64.
// ---------------------------------------------------------------------------
template <typename OutT>
__global__ __launch_bounds__(256) void gemm_mfma(const bf16_t* __restrict__ A,
                                                 const bf16_t* __restrict__ Wt,
                                                 const float* __restrict__ bias,
                                                 OutT* __restrict__ C,
                                                 int M, int Nout, int K) {
    __shared__ __align__(16) bf16_t As[128][32];
    __shared__ __align__(16) bf16_t Bs[128][32];
    const int tid  = threadIdx.x;
    const int lane = tid & 63;
    const int wv   = tid >> 6;
    const int ln   = lane & 15;
    const int ko   = lane >> 4;
    const int wr   = (wv >> 1) * 64;
    const int wc   = (wv & 1) * 64;
    const size_t bm = (size_t)blockIdx.x * 128;
    const size_t bn = (size_t)blockIdx.y * 128;

    // staging geometry: wave w stages rows [w*16, w*16+16) and +64 of each tile
    const int srow = wv * 16 + (lane >> 2);
    const int scol = (lane & 3) * 8;
    const bf16_t* gA0 = A  + (bm + srow) * K + scol;
    const bf16_t* gA1 = gA0 + (size_t)64 * K;
    const bf16_t* gB0 = Wt + (bn + srow) * K + scol;
    const bf16_t* gB1 = gB0 + (size_t)64 * K;
    bf16_t* lA0 = &As[srow][scol];
    bf16_t* lA1 = &As[srow + 64][scol];
    bf16_t* lB0 = &Bs[srow][scol];
    bf16_t* lB1 = &Bs[srow + 64][scol];

    f32x4 acc[4][4];
    #pragma unroll
    for (int i = 0; i < 4; i++)
        #pragma unroll
        for (int j = 0; j < 4; j++)
            acc[i][j] = (f32x4){0.f, 0.f, 0.f, 0.f};

    for (int k0 = 0; k0 < K; k0 += 32) {
        gl2lds(gA0 + k0, lA0);
        gl2lds(gA1 + k0, lA1);
        gl2lds(gB0 + k0, lB0);
        gl2lds(gB1 + k0, lB1);
        __syncthreads();
        bf16x8 af[4], bfr[4];
        #pragma unroll
        for (int i = 0; i < 4; i++)
            af[i] = *(const bf16x8*)&As[wr + i * 16 + ln][ko * 8];
        #pragma unroll
        for (int j = 0; j < 4; j++)
            bfr[j] = *(const bf16x8*)&Bs[wc + j * 16 + ln][ko * 8];
        #pragma unroll
        for (int i = 0; i < 4; i++)
            #pragma unroll
            for (int j = 0; j < 4; j++)
                acc[i][j] = mfma16(af[i], bfr[j], acc[i][j]);
        __syncthreads();
    }

    #pragma unroll
    for (int j = 0; j < 4; j++) {
        const size_t col = bn + wc + j * 16 + ln;
        const float bcol = bias[col];
        #pragma unroll
        for (int i = 0; i < 4; i++)
            #pragma unroll
            for (int r = 0; r < 4; r++) {
                const size_t row = bm + wr + i * 16 + ko * 4 + r;
                C[row * Nout + col] = (OutT)(acc[i][j][r] + bcol);
            }
    }
}

// ---------------------------------------------------------------------------
// MFMA attention, one block (4 waves) per (b,h).
// k-permuted shared layout for P and Vt: kk = (k%16)*16 + k/16, so the
// P C->A-layout round-trip is 2x ds_write_b128 per acc row (MFMA is
// permutation-invariant in k as long as P and V agree).
// ---------------------------------------------------------------------------
__global__ __launch_bounds__(256) void attn_mfma(const bf16_t* __restrict__ qkv,
                                                 const bf16_t* __restrict__ biasmat,
                                                 bf16_t* __restrict__ out) {
    const int b = blockIdx.x / H_;
    const int h = blockIdx.x % H_;
    __shared__ __align__(16) bf16_t Ks[NP_][32];        // 13312 B
    __shared__ __align__(16) bf16_t Vt[VD_][VSTR_];     // 16896 B
    __shared__ __align__(16) bf16_t Pb[4][16][VSTR_];   // 33792 B
    const int tid  = threadIdx.x;
    const int lane = tid & 63;
    const int wv   = tid >> 6;
    const int ln   = lane & 15;
    const int ko   = lane >> 4;

    // --- stage K via global_load_lds (13 chunks of 16 rows; padded rows read
    // neighbor data, killed later by -1e30 bias) ---
    {
        const int rsub = lane >> 2;
        const int col  = (lane & 3) * 8;
        for (int c = wv; c < 13; c += 4) {
            const int row = c * 16 + rsub;
            gl2lds(qkv + ((size_t)(b * N_ + row) * H_ + h) * 96 + KD_ + col,
                   &Ks[row][col]);
        }
    }
    // --- stage V transposed+permuted: key m -> column kk=(m%16)*16+m/16 ---
    if (tid < 224) {
        const int m  = tid;
        const int kk = (m & 15) * 16 + (m >> 4);
        const bf16_t* src = qkv + ((size_t)(b * N_ + m) * H_ + h) * 96 + 2 * KD_;
        #pragma unroll
        for (int c4 = 0; c4 < 4; c4++) {
            bf16x8 v8 = {bf16_t(0), bf16_t(0), bf16_t(0), bf16_t(0),
                         bf16_t(0), bf16_t(0), bf16_t(0), bf16_t(0)};
            if (m < N_) v8 = *(const bf16x8*)(src + c4 * 8);
            #pragma unroll
            for (int j = 0; j < 8; j++) Vt[c4 * 8 + j][kk] = v8[j];
        }
    }
    // --- zero Vt pad columns c=14,15 (kk = q*16+14/15) so 0*garbage != NaN ---
    for (int e = tid; e < 32 * 32; e += 256) {
        const int v = e >> 5;
        const int s = e & 31;
        Vt[v][(s >> 1) * 16 + 14 + (s & 1)] = bf16_t(0);
    }
    __syncthreads();

    // hoist K fragments into registers (reused across all t-tiles)
    bf16x8 kf[13];
    #pragma unroll
    for (int c = 0; c < 13; c++)
        kf[c] = *(const bf16x8*)&Ks[c * 16 + ln][ko * 8];

    for (int t = wv; t < 13; t += 4) {
        const int qrow = t * 16 + ln;
        const bf16x8 qf =
            *(const bf16x8*)(qkv + ((size_t)(b * N_ + qrow) * H_ + h) * 96 + ko * 8);

        f32x4 sc[13];
        #pragma unroll
        for (int c = 0; c < 13; c++) {
            f32x4 z = {0.f, 0.f, 0.f, 0.f};
            sc[c] = mfma16(qf, kf[c], z);
        }

        // scale + bias + row max
        float mx[4] = {-1e30f, -1e30f, -1e30f, -1e30f};
        #pragma unroll
        for (int r = 0; r < 4; r++) {
            const int rowc = min(t * 16 + ko * 4 + r, N_ - 1);
            const bf16_t* brow = biasmat + (size_t)(h * N_ + rowc) * NP_;
            #pragma unroll
            for (int c = 0; c < 13; c++) {
                const float s = sc[c][r] * SCALE_ + (float)brow[c * 16 + ln];
                sc[c][r] = s;
                mx[r] = fmaxf(mx[r], s);
            }
        }
        #pragma unroll
        for (int r = 0; r < 4; r++) {
            float m = mx[r];
            m = fmaxf(m, __shfl_xor(m, 1));
            m = fmaxf(m, __shfl_xor(m, 2));
            m = fmaxf(m, __shfl_xor(m, 4));
            m = fmaxf(m, __shfl_xor(m, 8));
            mx[r] = m;
        }
        float inv[4];
        #pragma unroll
        for (int r = 0; r < 4; r++) {
            float sum = 0.f;
            #pragma unroll
            for (int c = 0; c < 13; c++) {
                const float p = __expf(sc[c][r] - mx[r]);
                sc[c][r] = p;
                sum += p;
            }
            sum += __shfl_xor(sum, 1);
            sum += __shfl_xor(sum, 2);
            sum += __shfl_xor(sum, 4);
            sum += __shfl_xor(sum, 8);
            inv[r] = 1.f / sum;
        }
        // write unnormalized P~ into permuted layout: lane ln owns kk-slots
        // [ln*16, ln*16+16) (c-direction contiguous) => 2x b128 per row
        #pragma unroll
        for (int r = 0; r < 4; r++) {
            bf16x8 pa, pb;
            #pragma unroll
            for (int c = 0; c < 8; c++) pa[c] = (bf16_t)sc[c][r];
            #pragma unroll
            for (int c = 8; c < 13; c++) pb[c - 8] = (bf16_t)sc[c][r];
            pb[5] = bf16_t(0); pb[6] = bf16_t(0); pb[7] = bf16_t(0);
            *(bf16x8*)&Pb[wv][ko * 4 + r][ln * 16]     = pa;
            *(bf16x8*)&Pb[wv][ko * 4 + r][ln * 16 + 8] = pb;
        }
        __builtin_amdgcn_s_waitcnt(0);   // same-wave LDS RAW

        // PV over permuted k (256 slots = 8 MFMAs), two 16-wide v tiles
        f32x4 o0 = {0.f, 0.f, 0.f, 0.f};
        f32x4 o1 = {0.f, 0.f, 0.f, 0.f};
        #pragma unroll
        for (int kb = 0; kb < 8; kb++) {
            const bf16x8 pf = *(const bf16x8*)&Pb[wv][ln][kb * 32 + ko * 8];
            const bf16x8 v0 = *(const bf16x8*)&Vt[ln][kb * 32 + ko * 8];
            const bf16x8 v1 = *(const bf16x8*)&Vt[16 + ln][kb * 32 + ko * 8];
            o0 = mfma16(pf, v0, o0);
            o1 = mfma16(pf, v1, o1);
        }
        #pragma unroll
        for (int r = 0; r < 4; r++) {
            const int row = t * 16 + ko * 4 + r;
            if (row < N_) {
                const size_t ob = (size_t)(b * N_ + row) * DIM_ + h * VD_;
                out[ob + ln]      = (bf16_t)(o0[r] * inv[r]);
                out[ob + 16 + ln] = (bf16_t)(o1[r] * inv[r]);
            }
        }
    }
}

// ---------------------------------------------------------------------------
extern "C" void kernel_launch(void* const* d_in, const int* in_sizes, int n_in,
                              void* d_out, int out_size, void* d_ws, size_t ws_size,
                              hipStream_t stream) {
    const float* x        = (const float*)d_in[0];
    const float* norm_w   = (const float*)d_in[1];
    const float* norm_b   = (const float*)d_in[2];
    const float* qkv_w    = (const float*)d_in[3];
    const float* qkv_b    = (const float*)d_in[4];
    const float* att_bias = (const float*)d_in[5];
    const float* proj_w   = (const float*)d_in[6];
    const float* proj_b   = (const float*)d_in[7];
    const int*   bias_idx = (const int*)d_in[8];
    float* out = (float*)d_out;

    char* ws = (char*)d_ws;
    size_t off = 0;
    bf16_t* xn       = (bf16_t*)(ws + off); off += (size_t)ROWS_ * DIM_ * 2;
    bf16_t* qkvbuf   = (bf16_t*)(ws + off); off += (size_t)ROWS_ * F_ * 2;
    bf16_t* attn_out = (bf16_t*)(ws + off); off += (size_t)ROWS_ * DIM_ * 2;
    bf16_t* biasmat  = (bf16_t*)(ws + off); off += (size_t)H_ * N_ * NP_ * 2;
    bf16_t* wq_bf    = (bf16_t*)(ws + off); off += (size_t)F_ * DIM_ * 2;
    bf16_t* wp_bf    = (bf16_t*)(ws + off); off += (size_t)DIM_ * DIM_ * 2;

    cvt_w<<<(F_ * DIM_) / 1024, 256, 0, stream>>>(qkv_w, wq_bf);
    cvt_w<<<(DIM_ * DIM_) / 1024, 256, 0, stream>>>(proj_w, wp_bf);
    ln_kernel<<<ROWS_ / 4, 256, 0, stream>>>(x, norm_w, norm_b, xn);
    bias_gather<<<(H_ * N_ * NP_ + 255) / 256, 256, 0, stream>>>(att_bias, bias_idx, biasmat);
    gemm_mfma<bf16_t><<<dim3(ROWS_ / 128, F_ / 128), 256, 0, stream>>>(
        xn, wq_bf, qkv_b, qkvbuf, ROWS_, F_, DIM_);
    attn_mfma<<<B_ * H_, 256, 0, stream>>>(qkvbuf, biasmat, attn_out);
    gemm_mfma<float><<<dim3(ROWS_ / 128, DIM_ / 128), 256, 0, stream>>>(
        attn_out, wp_bf, proj_b, out, ROWS_, DIM_, DIM_);
}